// Round 6
// baseline (336.040 us; speedup 1.0000x reference)
//
#include <hip/hip_runtime.h>
#include <hip/hip_bf16.h>

// Problem constants
#define NB     8
#define NPTS   4096
#define DIMC   64
#define KNN_K  8
#define NBLK   12
#define NREP   8      // stats replicas (atomic de-contention)

// ---------------------------------------------------------------------------
// Kernel 0: precompute (x, y, z, |x|^2) per point for the KNN kernel, fused
// with zeroing the stats buffers (ws is 0xAA-poisoned before every launch).
// sq formula matches numpy bit-for-bit (contract off, sequential adds).
// Grid: 128 WGs x 256 thr (32768 threads >= 13312 stats floats).
// ---------------------------------------------------------------------------
__global__ __launch_bounds__(256) void prep_kernel(
        const float* __restrict__ xyz, float4* __restrict__ pts4g,
        float* __restrict__ stats) {
#pragma clang fp contract(off)
    int g = blockIdx.x * 256 + threadIdx.x;      // 0..32767
    if (g < 13 * NREP * 128) stats[g] = 0.0f;
    int b = g >> 12, j = g & 4095;
    const float* xb = xyz + (size_t)b * 3 * NPTS;
    float x = xb[j];
    float y = xb[NPTS + j];
    float z = xb[2 * NPTS + j];
    float sq = (x * x + y * y) + z * z;
    pts4g[g] = make_float4(x, y, z, sq);
}

// ---------------------------------------------------------------------------
// Kernel 1: transpose fp32 points [b][d][n] -> point-major P0[b][n][d],
// fused with stats[0] accumulation. XCD-affine: b = blockIdx & 7 so batch
// b's P-slice is written from XCD b's CUs and stays in its L2.
// Grid: 512 WGs, 256 threads.
// ---------------------------------------------------------------------------
__global__ __launch_bounds__(256) void cast_kernel(
        const float* __restrict__ pts,
        float* __restrict__ P0, float* __restrict__ stats0) {
    __shared__ __align__(16) float tr[64 * 65];      // [d][n] transpose tile (+1 pad)
    __shared__ float slotA[4 * 64], slotB[4 * 64];
    int wg = blockIdx.x;
    int b = wg & 7;                  // XCD affinity
    int n0 = (wg >> 3) << 6;
    int rep = (wg >> 3) & (NREP - 1);
    int tid = threadIdx.x;
    int lane6 = tid & 63;
    int grp = tid >> 6;              // 0..3

    #pragma unroll
    for (int k = 0; k < 16; ++k) {
        int d = grp + (k << 2);
        float v = pts[(((size_t)((b << 6) + d)) << 12) + n0 + lane6];
        tr[d * 65 + lane6] = v;
    }
    __syncthreads();
    int c = lane6;
    float s = 0.0f, s2 = 0.0f;
    #pragma unroll
    for (int k = 0; k < 16; ++k) {
        int p = grp + (k << 2);
        float v = tr[c * 65 + p];
        P0[((size_t)((b << 12) + n0 + p)) * 64 + c] = v;
        s += v; s2 += v * v;
    }
    slotA[grp * 64 + c] = s;
    slotB[grp * 64 + c] = s2;
    __syncthreads();
    if (tid < 64) {
        float t = slotA[tid] + slotA[64 + tid] + slotA[128 + tid] + slotA[192 + tid];
        atomicAdd(&stats0[rep * 128 + tid], t);
    } else if (tid < 128) {
        int cc = tid - 64;
        float t = slotB[cc] + slotB[64 + cc] + slotB[128 + cc] + slotB[192 + cc];
        atomicAdd(&stats0[rep * 128 + 64 + cc], t);
    }
}

// ---------------------------------------------------------------------------
// Kernel 2: brute-force 8-NN, one query per lane, f64-key top-8.
// Round-5 was GRID-bound (256 WGs on 256 CUs -> 1 WG/CU, 2 waves/SIMD,
// VALUBusy 74%). Now: WG = 64 queries (8 b x 64 tiles = 512 WGs), 512 thr;
// wave = chunk c in 0..7 scanning 256 candidates per staged half (512
// total). LDS 68 KB -> 2 WG/CU -> 4 waves/SIMD.
// key = f64(d2) | idx (12 low mantissa bits; order-preserving, ties ->
// lower idx, matching top_k stability). Insert = branch-gated fmin/fmax
// chain. 8 chunk-partials merged by key = exact lexicographic (d2, idx)
// = exact single-scan order (chunk/half interleaving irrelevant).
// d2 formula matches numpy bit-for-bit: contract off, sequential dot,
// d2 = (sq_i - 2*dot) + sq_j.
// ---------------------------------------------------------------------------
__global__ __launch_bounds__(512) void knn_kernel(
        const float4* __restrict__ pts4g, int* __restrict__ idx) {
#pragma clang fp contract(off)
    __shared__ __align__(16) float4 cand[2048];      // 32 KB
    __shared__ double stash[8 * 9 * 64];             // 36 KB
    int wg = blockIdx.x;
    int b = wg >> 6;
    int q0 = (wg & 63) << 6;
    int tid = threadIdx.x;                           // 0..511

    int lane  = tid & 63;            // query within tile
    int chunk = tid >> 6;            // 0..7

    const float4* cb = pts4g + ((size_t)b << 12);
    float4 qp = cb[q0 + lane];

    double k0, k1, k2, k3, k4, k5, k6, k7;
    k0 = k1 = k2 = k3 = k4 = k5 = k6 = k7 = __builtin_inf();
    float bd7f = 3.4e38f;

    for (int half = 0; half < 2; ++half) {
        if (half) __syncthreads();                   // drain readers before restage
        #pragma unroll
        for (int k = 0; k < 4; ++k)
            cand[tid + (k << 9)] = cb[(half << 11) + tid + (k << 9)];
        __syncthreads();

        int jl0 = chunk << 8;                        // 256 candidates per chunk
        int jg0 = (half << 11) | jl0;                // global candidate index
        for (int jo = 0; jo < 256; jo += 8) {
            float d2v[8];
            #pragma unroll
            for (int u = 0; u < 8; ++u) {
                float4 p = cand[jl0 + jo + u];
                float dot = (qp.x * p.x + qp.y * p.y) + qp.z * p.z;
                d2v[u] = (qp.w - 2.0f * dot) + p.w;
            }
            #pragma unroll
            for (int u = 0; u < 8; ++u) {
                float d2 = d2v[u];
                if (d2 < bd7f) {
                    unsigned long long kb =
                        __double_as_longlong((double)d2) |
                        (unsigned long long)(jg0 + jo + u);
                    double key = __longlong_as_double(kb);
                    double n0 = fmin(k0, key);
                    double n1 = fmin(k1, fmax(k0, key));
                    double n2 = fmin(k2, fmax(k1, key));
                    double n3 = fmin(k3, fmax(k2, key));
                    double n4 = fmin(k4, fmax(k3, key));
                    double n5 = fmin(k5, fmax(k4, key));
                    double n6 = fmin(k6, fmax(k5, key));
                    double n7 = fmin(k7, fmax(k6, key));
                    k0 = n0; k1 = n1; k2 = n2; k3 = n3;
                    k4 = n4; k5 = n5; k6 = n6; k7 = n7;
                    bd7f = (float)k7;    // exact: idx bits << half-ulp of f32
                }
            }
        }
    }

    {
        double* S = &stash[(chunk * 9) * 64 + lane];
        S[0 * 64] = k0; S[1 * 64] = k1; S[2 * 64] = k2; S[3 * 64] = k3;
        S[4 * 64] = k4; S[5 * 64] = k5; S[6 * 64] = k6; S[7 * 64] = k7;
        S[8 * 64] = __builtin_inf();    // merge guard
    }
    __syncthreads();

    // 8-way merge per query by key (threads 0..63)
    if (tid < 64) {
        int h0 = 0, h1 = 0, h2 = 0, h3 = 0, h4 = 0, h5 = 0, h6 = 0, h7 = 0;
        int* op = idx + ((size_t)(b * NPTS + q0 + tid)) * 8;
        #pragma unroll
        for (int t = 0; t < 8; ++t) {
            double v0 = stash[(0 * 9 + h0) * 64 + tid];
            double v1 = stash[(1 * 9 + h1) * 64 + tid];
            double v2 = stash[(2 * 9 + h2) * 64 + tid];
            double v3 = stash[(3 * 9 + h3) * 64 + tid];
            double v4 = stash[(4 * 9 + h4) * 64 + tid];
            double v5 = stash[(5 * 9 + h5) * 64 + tid];
            double v6 = stash[(6 * 9 + h6) * 64 + tid];
            double v7 = stash[(7 * 9 + h7) * 64 + tid];
            double best = v0; int bc = 0;
            if (v1 < best) { best = v1; bc = 1; }
            if (v2 < best) { best = v2; bc = 2; }
            if (v3 < best) { best = v3; bc = 3; }
            if (v4 < best) { best = v4; bc = 4; }
            if (v5 < best) { best = v5; bc = 5; }
            if (v6 < best) { best = v6; bc = 6; }
            if (v7 < best) { best = v7; bc = 7; }
            h0 += (bc == 0); h1 += (bc == 1); h2 += (bc == 2); h3 += (bc == 3);
            h4 += (bc == 4); h5 += (bc == 5); h6 += (bc == 6); h7 += (bc == 7);
            op[t] = (int)(__double_as_longlong(best) & 0xFFFULL);
        }
    }
}

// ---------------------------------------------------------------------------
// Kernel 3 (x12): one residual block, fully fused. XCD-affine b = wg & 7.
// 512 threads (was 256): 2 pts/thread gather + 4o x 2pt GEMM tile ->
// 4096 waves -> 4 waves/SIMD at 2 WG/CU (LDS ~58 KB) to hide the ~200-cyc
// L2 gather latency (round-5 blocks were latency-bound at 2 waves/SIMD).
//   - self rows staged once in LDS (serves h_self AND the residual)
//   - BN affine from 8-replica stats (summed here)
//   - stats for NEXT block -> replica (wg>>3)&7
//   - last block: fp32 output in [b][d][n] via LDS transpose
// Grid: 512 WGs (64 tiles x 8 b), 512 threads.
// ---------------------------------------------------------------------------
__global__ __launch_bounds__(512) void block_kernel(
        const float* __restrict__ Pin, float* __restrict__ Pout,
        const float* __restrict__ statsIn, float* __restrict__ statsOut,
        const float* __restrict__ Wp, const float* __restrict__ Bp,
        const float* __restrict__ Gp, const float* __restrict__ Betap,
        const int* __restrict__ gidx, float* __restrict__ dout, int last) {
    __shared__ __align__(16) float Wt[64 * 68];      // W transposed: Wt[d][o]
    __shared__ __align__(16) float mt[64 * 68];      // m[d][pt]
    __shared__ __align__(16) float selft[64 * 64];   // raw self rows [pt][c]
    __shared__ __align__(16) int   idxl[64 * 8];
    __shared__ __align__(16) float scale_l[64], shift_l[64], bias_l[64];
    __shared__ float slot[8 * 128];

    int wg = blockIdx.x;
    int b = wg & 7;                  // XCD affinity
    int n0 = (wg >> 3) << 6;
    int rep = (wg >> 3) & (NREP - 1);
    int tid = threadIdx.x;           // 0..511

    const float* Pb = Pin + (((size_t)b) << 18);     // batch slice [4096][64]

    // --- setup: idx tile, self tile, W^T, BN affine (replica-summed) ---
    if (tid < 128) {
        ((int4*)idxl)[tid] = ((const int4*)(gidx + ((size_t)(b * NPTS + n0)) * 8))[tid];
    }
    #pragma unroll
    for (int k = 0; k < 2; ++k) {    // self rows: 64 pts x 64 ch, coalesced
        int lin = tid + (k << 9);    // float4 id
        ((float4*)selft)[lin] = ((const float4*)&Pb[(size_t)n0 << 6])[lin];
    }
    #pragma unroll
    for (int k = 0; k < 8; ++k) {
        int lin = tid + (k << 9);
        int o = lin >> 6, d = lin & 63;
        Wt[d * 68 + o] = Wp[lin];
    }
    if (tid < 64) {
        int c = tid;
        float sum = 0.0f, sumsq = 0.0f;
        #pragma unroll
        for (int r = 0; r < NREP; ++r) {
            sum   += statsIn[r * 128 + c];
            sumsq += statsIn[r * 128 + 64 + c];
        }
        float mean = sum * (1.0f / 32768.0f);
        float var  = sumsq * (1.0f / 32768.0f) - mean * mean;
        float rs   = 1.0f / sqrtf(var + 1e-5f);
        float sc   = Gp[c] * rs;
        scale_l[c] = sc;
        shift_l[c] = Betap[c] - mean * sc;
        bias_l[c]  = Bp[c];
    }
    __syncthreads();

    // --- gather: m[d][pt]; self from LDS, 8 neighbors from local-L2 global ---
    {
        int cq = tid & 15;           // channel quad: channels 4cq..4cq+3
        int pp = tid >> 4;           // 0..31: points 2pp, 2pp+1
        int c4 = cq << 2;
        float4 sc4 = *(const float4*)&scale_l[c4];
        float4 sh4 = *(const float4*)&shift_l[c4];
        #pragma unroll
        for (int i = 0; i < 2; ++i) {
            int pt = (pp << 1) + i;
            int4 ja = *(const int4*)&idxl[pt * 8];
            int4 jb = *(const int4*)&idxl[pt * 8 + 4];
            float4 v[9];
            v[0] = *(const float4*)&selft[(pt << 6) + c4];
            v[1] = *(const float4*)&Pb[(((size_t)ja.x) << 6) + c4];
            v[2] = *(const float4*)&Pb[(((size_t)ja.y) << 6) + c4];
            v[3] = *(const float4*)&Pb[(((size_t)ja.z) << 6) + c4];
            v[4] = *(const float4*)&Pb[(((size_t)ja.w) << 6) + c4];
            v[5] = *(const float4*)&Pb[(((size_t)jb.x) << 6) + c4];
            v[6] = *(const float4*)&Pb[(((size_t)jb.y) << 6) + c4];
            v[7] = *(const float4*)&Pb[(((size_t)jb.z) << 6) + c4];
            v[8] = *(const float4*)&Pb[(((size_t)jb.w) << 6) + c4];
            float4 a = make_float4(0.f, 0.f, 0.f, 0.f);
            #pragma unroll
            for (int k = 0; k < 9; ++k) {
                float hx = v[k].x * sc4.x + sh4.x;
                float hy = v[k].y * sc4.y + sh4.y;
                float hz = v[k].z * sc4.z + sh4.z;
                float hw = v[k].w * sc4.w + sh4.w;
                a.x += fmaxf(hx, 0.01f * hx);
                a.y += fmaxf(hy, 0.01f * hy);
                a.z += fmaxf(hz, 0.01f * hz);
                a.w += fmaxf(hw, 0.01f * hw);
            }
            mt[(c4 + 0) * 68 + pt] = a.x * (1.0f / 9.0f);
            mt[(c4 + 1) * 68 + pt] = a.y * (1.0f / 9.0f);
            mt[(c4 + 2) * 68 + pt] = a.z * (1.0f / 9.0f);
            mt[(c4 + 3) * 68 + pt] = a.w * (1.0f / 9.0f);
        }
    }
    __syncthreads();

    // --- GEMM: out[pt][o] = sum_d Wt[d][o] * m[d][pt] + bias[o] ---
    int o0 = (tid & 15) << 2;
    int p0 = (tid >> 4) << 1;        // 2 pts
    float4 acc[2];
    {
        float4 bias4 = *(const float4*)&bias_l[o0];
        acc[0] = bias4; acc[1] = bias4;
    }
    #pragma unroll
    for (int d = 0; d < 64; ++d) {
        float4 wv = *(const float4*)&Wt[d * 68 + o0];
        float2 a  = *(const float2*)&mt[d * 68 + p0];
        acc[0].x += wv.x * a.x; acc[0].y += wv.y * a.x; acc[0].z += wv.z * a.x; acc[0].w += wv.w * a.x;
        acc[1].x += wv.x * a.y; acc[1].y += wv.y * a.y; acc[1].z += wv.z * a.y; acc[1].w += wv.w * a.y;
    }

    // --- residual add (self rows from LDS) ---
    #pragma unroll
    for (int j = 0; j < 2; ++j) {
        float4 r = *(const float4*)&selft[((p0 + j) << 6) + o0];
        acc[j].x += r.x; acc[j].y += r.y; acc[j].z += r.z; acc[j].w += r.w;
    }

    if (!last) {
        float* PbOut = Pout + ((((size_t)b) << 12) + n0) * 64;
        #pragma unroll
        for (int j = 0; j < 2; ++j)
            *(float4*)&PbOut[((size_t)(p0 + j)) * 64 + o0] = acc[j];

        // stats for next block: per-thread sums over 2 pts; lanes ^16,^32
        // share the o-quad within a wave -> per-wave per-channel partials
        float4 s, s2;
        s.x = acc[0].x + acc[1].x;  s.y = acc[0].y + acc[1].y;
        s.z = acc[0].z + acc[1].z;  s.w = acc[0].w + acc[1].w;
        s2.x = acc[0].x*acc[0].x + acc[1].x*acc[1].x;
        s2.y = acc[0].y*acc[0].y + acc[1].y*acc[1].y;
        s2.z = acc[0].z*acc[0].z + acc[1].z*acc[1].z;
        s2.w = acc[0].w*acc[0].w + acc[1].w*acc[1].w;
        #pragma unroll
        for (int m = 16; m <= 32; m <<= 1) {
            s.x += __shfl_xor(s.x, m, 64);  s.y += __shfl_xor(s.y, m, 64);
            s.z += __shfl_xor(s.z, m, 64);  s.w += __shfl_xor(s.w, m, 64);
            s2.x += __shfl_xor(s2.x, m, 64); s2.y += __shfl_xor(s2.y, m, 64);
            s2.z += __shfl_xor(s2.z, m, 64); s2.w += __shfl_xor(s2.w, m, 64);
        }
        if ((tid & 63) < 16) {
            int w = tid >> 6;        // wave 0..7
            slot[w * 128 + o0 + 0] = s.x;  slot[w * 128 + o0 + 1] = s.y;
            slot[w * 128 + o0 + 2] = s.z;  slot[w * 128 + o0 + 3] = s.w;
            slot[w * 128 + 64 + o0 + 0] = s2.x; slot[w * 128 + 64 + o0 + 1] = s2.y;
            slot[w * 128 + 64 + o0 + 2] = s2.z; slot[w * 128 + 64 + o0 + 3] = s2.w;
        }
        __syncthreads();
        if (tid < 128) {
            float t = 0.0f;
            #pragma unroll
            for (int w = 0; w < 8; ++w) t += slot[w * 128 + tid];
            atomicAdd(&statsOut[rep * 128 + tid], t);
        }
    } else {
        __syncthreads();                         // all mt reads done
        float* stage = mt;                       // reuse as [o][pt], 16 KB
        #pragma unroll
        for (int j = 0; j < 2; ++j) {
            stage[(o0 + 0) * 64 + p0 + j] = acc[j].x;
            stage[(o0 + 1) * 64 + p0 + j] = acc[j].y;
            stage[(o0 + 2) * 64 + p0 + j] = acc[j].z;
            stage[(o0 + 3) * 64 + p0 + j] = acc[j].w;
        }
        __syncthreads();
        #pragma unroll
        for (int k = 0; k < 8; ++k) {
            int lin = tid + (k << 9);
            int o = lin >> 6, pt = lin & 63;
            dout[(((size_t)((b << 6) + o)) << 12) + n0 + pt] = stage[lin];
        }
    }
}

// ---------------------------------------------------------------------------
extern "C" void kernel_launch(void* const* d_in, const int* in_sizes, int n_in,
                              void* d_out, int out_size, void* d_ws, size_t ws_size,
                              hipStream_t stream) {
    const float* xyz    = (const float*)d_in[0];
    const float* pts    = (const float*)d_in[1];
    const float* conv_w = (const float*)d_in[2];
    const float* conv_b = (const float*)d_in[3];
    const float* gamma  = (const float*)d_in[4];
    const float* beta   = (const float*)d_in[5];
    float* out = (float*)d_out;

    char* ws = (char*)d_ws;
    float*  P0    = (float*)(ws);                                  //  8 MB
    float*  P1    = (float*)(ws + (size_t)8 * 1024 * 1024);        //  8 MB
    int*    idx   = (int*)  (ws + (size_t)16 * 1024 * 1024);       //  1 MB
    float*  stats = (float*)(ws + (size_t)17 * 1024 * 1024);       // 52 KB
    float4* pts4g = (float4*)(ws + (size_t)18 * 1024 * 1024);      // 512 KB

    prep_kernel<<<128, 256, 0, stream>>>(xyz, pts4g, stats);
    cast_kernel<<<512, 256, 0, stream>>>(pts, P0, stats);
    knn_kernel<<<512, 512, 0, stream>>>(pts4g, idx);

    float* Pbuf[2] = {P0, P1};
    for (int t = 0; t < NBLK; ++t) {
        block_kernel<<<512, 512, 0, stream>>>(
            Pbuf[t & 1], Pbuf[(t + 1) & 1],
            stats + (size_t)t * NREP * 128, stats + (size_t)(t + 1) * NREP * 128,
            conv_w + (size_t)t * 4096, conv_b + (size_t)t * 64,
            gamma + (size_t)t * 64, beta + (size_t)t * 64,
            idx, out, (t == NBLK - 1) ? 1 : 0);
    }
}